// Round 5
// baseline (936.045 us; speedup 1.0000x reference)
//
#include <hip/hip_runtime.h>
#include <hip/hip_bf16.h>
#include <math.h>

#define HH 128
#define FF 128
#define GG 50
#define NLAYERS 6

typedef __attribute__((ext_vector_type(8))) short bf16x8;
typedef __attribute__((ext_vector_type(4))) float f32x4;

static __device__ __forceinline__ float ssp(float x) {
    return fmaxf(x, 0.f) + __logf(1.f + __expf(-fabsf(x))) - 0.6931471805599453f;
}

static __device__ __forceinline__ short f2bf(float x) {
    union { float f; unsigned u; } c; c.f = x;
    unsigned r = (c.u + 0x7FFF + ((c.u >> 16) & 1)) >> 16;
    return (short)r;
}

static __device__ __forceinline__ float bf2f_lo(unsigned p) {
    union { unsigned u; float f; } c; c.u = p << 16; return c.f;
}
static __device__ __forceinline__ float bf2f_hi(unsigned p) {
    union { unsigned u; float f; } c; c.u = p & 0xFFFF0000u; return c.f;
}

// ---------------- sort pipeline: hist -> scan -> scatter ----------------
__global__ void hist_kernel(const int* __restrict__ col, int* __restrict__ counts, int E_) {
    int e = blockIdx.x * 256 + threadIdx.x;
    if (e < E_) atomicAdd(&counts[col[e]], 1);
}

__global__ __launch_bounds__(1024) void scan_kernel(const int* __restrict__ counts,
                                                    int* __restrict__ offsets, int N_) {
    __shared__ int wsum[16];
    __shared__ int carry_s;
    const int tid = threadIdx.x;
    const int lane = tid & 63, wid = tid >> 6;
    if (tid == 0) carry_s = 0;
    __syncthreads();
    for (int base = 0; base < N_; base += 1024) {
        int i = base + tid;
        int val = (i < N_) ? counts[i] : 0;
        int x = val;
#pragma unroll
        for (int d = 1; d < 64; d <<= 1) {
            int t = __shfl_up(x, d, 64);
            if (lane >= d) x += t;
        }
        if (lane == 63) wsum[wid] = x;
        int carry = carry_s;
        __syncthreads();
        if (wid == 0) {
            int s = (lane < 16) ? wsum[lane] : 0;
#pragma unroll
            for (int d = 1; d < 16; d <<= 1) {
                int t = __shfl_up(s, d, 64);
                if (lane >= d) s += t;
            }
            if (lane < 16) wsum[lane] = s;
            if (lane == 15) carry_s = carry + s;
        }
        __syncthreads();
        int woffset = (wid > 0) ? wsum[wid - 1] : 0;
        if (i < N_) offsets[i] = carry + woffset + x - val;  // exclusive
        __syncthreads();
    }
}

__global__ void scatter_kernel(const float* __restrict__ pos,
                               const float* __restrict__ offs,
                               const int* __restrict__ row,
                               const int* __restrict__ col,
                               int* __restrict__ woff,
                               int* __restrict__ srow, int* __restrict__ scol,
                               float* __restrict__ sdist, float* __restrict__ sCb,
                               int E_) {
    int e = blockIdx.x * 256 + threadIdx.x;
    if (e >= E_) return;
    int r = row[e], c = col[e];
    float dx = pos[c * 3 + 0] + offs[e * 3 + 0] - pos[r * 3 + 0];
    float dy = pos[c * 3 + 1] + offs[e * 3 + 1] - pos[r * 3 + 1];
    float dz = pos[c * 3 + 2] + offs[e * 3 + 2] - pos[r * 3 + 2];
    float d = sqrtf(dx * dx + dy * dy + dz * dz);
    int p = atomicAdd(&woff[c], 1);
    srow[p] = r;
    scol[p] = c;
    sdist[p] = d;
    sCb[p] = 0.5f * (cosf(d * 0.6283185307179586f) + 1.0f);
}

// ------------- prep: transpose + bf16 all weights (all layers) -------------
__global__ __launch_bounds__(256) void prep_kernel(
    const float* __restrict__ w1, const float* __restrict__ w2,
    const float* __restrict__ u1, const float* __restrict__ u2,
    const float* __restrict__ lin_w,
    short* __restrict__ w1t, short* __restrict__ w2t,
    short* __restrict__ u1t, short* __restrict__ u2t, short* __restrict__ lin_wt) {
    int idx = blockIdx.x * 256 + threadIdx.x;
    if (idx < NLAYERS * FF * FF) {
        int l = idx >> 14, r = idx & 16383, a = r >> 7, b = r & 127;
        size_t src = (size_t)l * FF * FF + (size_t)b * FF + a;  // [l][b][a]
        w2t[idx] = f2bf(w2[src]);
        u1t[idx] = f2bf(u1[src]);
        u2t[idx] = f2bf(u2[src]);
        lin_wt[idx] = f2bf(lin_w[src]);
    }
    if (idx < NLAYERS * FF * 64) {
        int l = idx >> 13, r = idx & 8191, fo = r >> 6, g = r & 63;
        w1t[idx] = f2bf(g < GG ? w1[((size_t)l * GG + g) * FF + fo] : 0.f);
    }
}

// ---------------- vproj0 = v(f32) @ lin_w[0]  via MFMA, bf16 out ----------------
__global__ __launch_bounds__(256) void vproj0_kernel(const float* __restrict__ vb,
                                                     const short* __restrict__ lwt,
                                                     unsigned short* __restrict__ out,
                                                     int N_) {
    const int tid = threadIdx.x;
    const int lane = tid & 63, wave = tid >> 6;
    const int l15 = lane & 15, l4 = lane >> 4;
    const int n0 = wave * 32;
    const int nb0 = blockIdx.x * 64;
    bf16x8 bw[2][4];
#pragma unroll
    for (int n = 0; n < 2; n++)
#pragma unroll
        for (int ks = 0; ks < 4; ks++)
            bw[n][ks] = *(const bf16x8*)&lwt[(n0 + n * 16 + l15) * 128 + ks * 32 + l4 * 8];
#pragma unroll
    for (int m = 0; m < 4; m++) {
        f32x4 acc0 = {0.f, 0.f, 0.f, 0.f}, acc1 = {0.f, 0.f, 0.f, 0.f};
        int arow = nb0 + m * 16 + l15;
        const float* ap = &vb[(size_t)(arow < N_ ? arow : 0) * HH];
#pragma unroll
        for (int ks = 0; ks < 4; ks++) {
            float4 x0 = *(const float4*)&ap[ks * 32 + l4 * 8];
            float4 x1 = *(const float4*)&ap[ks * 32 + l4 * 8 + 4];
            bf16x8 a = {f2bf(x0.x), f2bf(x0.y), f2bf(x0.z), f2bf(x0.w),
                        f2bf(x1.x), f2bf(x1.y), f2bf(x1.z), f2bf(x1.w)};
            acc0 = __builtin_amdgcn_mfma_f32_16x16x32_bf16(a, bw[0][ks], acc0, 0, 0, 0);
            acc1 = __builtin_amdgcn_mfma_f32_16x16x32_bf16(a, bw[1][ks], acc1, 0, 0, 0);
        }
#pragma unroll
        for (int r = 0; r < 4; r++) {
            int gn = nb0 + m * 16 + l4 * 4 + r;
            if (gn < N_) {
                out[(size_t)gn * FF + n0 + l15] = (unsigned short)f2bf(acc0[r]);
                out[(size_t)gn * FF + n0 + 16 + l15] = (unsigned short)f2bf(acc1[r]);
            }
        }
    }
}

// ---------------- fused edge kernel (MFMA + sorted-run scatter) ----------------
// LDS: pool = union(h1 64x136, wf 64x132) bf16 + staged indices -> ~17.9 KB, 8 blk/CU
__global__ __launch_bounds__(256, 8) void edge_mfma_kernel(
    const float* __restrict__ sdist, const float* __restrict__ sCb,
    const unsigned short* __restrict__ vproj, const int* __restrict__ srow,
    const int* __restrict__ scol, const short* __restrict__ w1t,
    const float* __restrict__ b1, const short* __restrict__ w2t,
    const float* __restrict__ b2, float* __restrict__ agg, int E_) {
    __shared__ __align__(16) short lds_pool[64 * 136];
    __shared__ int srow_s[64], scol_s[64];
    short* h1_s = lds_pool;               // [64][136]
    short* wf_s = lds_pool;               // [64][132] alias, used after h1 reads done
    const int tid = threadIdx.x;
    const int lane = tid & 63, wave = tid >> 6;
    const int l15 = lane & 15, l4 = lane >> 4;
    const int n0 = wave * 32;
    const int e0 = blockIdx.x * 64;

    bf16x8 bw1[2][2], bw2[2][4];
    float bias1[2], bias2[2];
#pragma unroll
    for (int n = 0; n < 2; n++) {
        const int fo = n0 + n * 16 + l15;
        bias1[n] = b1[fo];
        bias2[n] = b2[fo];
#pragma unroll
        for (int ks = 0; ks < 2; ks++)
            bw1[n][ks] = *(const bf16x8*)&w1t[fo * 64 + ks * 32 + l4 * 8];
#pragma unroll
        for (int ks = 0; ks < 4; ks++)
            bw2[n][ks] = *(const bf16x8*)&w2t[fo * 128 + ks * 32 + l4 * 8];
    }

    if (tid < 64) {
        int ge = e0 + tid;
        if (ge >= E_) ge = E_ - 1;
        srow_s[tid] = srow[ge];
        scol_s[tid] = scol[ge];
    }

    // GEMM1: h1 = ssp(demb @ w1 + b1), demb computed in registers
    const float STEP = 5.0f / 49.0f;
    const float COEFF = -0.5f / (STEP * STEP);
#pragma unroll
    for (int m = 0; m < 4; m++) {
        int ge = e0 + m * 16 + l15;
        float d = sdist[ge < E_ ? ge : 0];
        bf16x8 a0, a1;
#pragma unroll
        for (int j = 0; j < 8; j++) {
            int g0 = l4 * 8 + j;                       // 0..31
            float x0 = fmaf((float)g0, -STEP, d);
            a0[j] = f2bf(__expf(COEFF * x0 * x0));
            int g1 = 32 + l4 * 8 + j;                  // 32..63
            float x1 = fmaf((float)g1, -STEP, d);
            a1[j] = (g1 < GG) ? f2bf(__expf(COEFF * x1 * x1)) : (short)0;
        }
#pragma unroll
        for (int n = 0; n < 2; n++) {
            f32x4 acc = {bias1[n], bias1[n], bias1[n], bias1[n]};
            acc = __builtin_amdgcn_mfma_f32_16x16x32_bf16(a0, bw1[n][0], acc, 0, 0, 0);
            acc = __builtin_amdgcn_mfma_f32_16x16x32_bf16(a1, bw1[n][1], acc, 0, 0, 0);
            const int f = n0 + n * 16 + l15;
#pragma unroll
            for (int r = 0; r < 4; r++)
                h1_s[(m * 16 + l4 * 4 + r) * 136 + f] = f2bf(ssp(acc[r]));
        }
    }
    __syncthreads();

    // GEMM2 into registers
    f32x4 accA[4], accB[4];
#pragma unroll
    for (int m = 0; m < 4; m++) {
        accA[m] = {bias2[0], bias2[0], bias2[0], bias2[0]};
        accB[m] = {bias2[1], bias2[1], bias2[1], bias2[1]};
#pragma unroll
        for (int ks = 0; ks < 4; ks++) {
            bf16x8 a = *(const bf16x8*)&h1_s[(m * 16 + l15) * 136 + ks * 32 + l4 * 8];
            accA[m] = __builtin_amdgcn_mfma_f32_16x16x32_bf16(a, bw2[0][ks], accA[m], 0, 0, 0);
            accB[m] = __builtin_amdgcn_mfma_f32_16x16x32_bf16(a, bw2[1][ks], accB[m], 0, 0, 0);
        }
    }
    __syncthreads();  // all h1 reads done; wf_s may alias

    // store Wf * C to LDS (bf16)
#pragma unroll
    for (int m = 0; m < 4; m++) {
#pragma unroll
        for (int r = 0; r < 4; r++) {
            int er = m * 16 + l4 * 4 + r;
            int ge = e0 + er;
            float cb = (ge < E_) ? sCb[ge] : 0.f;
            wf_s[er * 132 + n0 + l15] = f2bf(accA[m][r] * cb);
            wf_s[er * 132 + n0 + 16 + l15] = f2bf(accB[m][r] * cb);
        }
    }
    __syncthreads();

    // serial walk: 4 subs (waves) x 16 edges, features (2t, 2t+1) per thread
    {
        const int sub = tid >> 6;        // 0..3 (one wave each)
        const int t = tid & 63;          // feature pair index
        const int base = sub * 16;
        float acc0 = 0.f, acc1 = 0.f;
        int cur = scol_s[base];
#pragma unroll
        for (int i = 0; i < 16; i++) {
            int e = base + i;
            int r_ = srow_s[e], c_ = scol_s[e];
            unsigned wp = *(const unsigned*)&wf_s[e * 132 + 2 * t];
            unsigned vp = *(const unsigned*)&vproj[(size_t)r_ * FF + 2 * t];
            if (c_ != cur) {   // wave-uniform branch
                unsafeAtomicAdd(&agg[(size_t)cur * FF + 2 * t], acc0);
                unsafeAtomicAdd(&agg[(size_t)cur * FF + 2 * t + 1], acc1);
                acc0 = 0.f; acc1 = 0.f; cur = c_;
            }
            acc0 = fmaf(bf2f_lo(wp), bf2f_lo(vp), acc0);
            acc1 = fmaf(bf2f_hi(wp), bf2f_hi(vp), acc1);
        }
        unsafeAtomicAdd(&agg[(size_t)cur * FF + 2 * t], acc0);
        unsafeAtomicAdd(&agg[(size_t)cur * FF + 2 * t + 1], acc1);
    }
}

// ------- fused node kernel (32 rows/block): v += ssp(agg@u1+b)@u2+b ; vproj_next
__global__ __launch_bounds__(256) void node_mfma_kernel(
    const float* __restrict__ agg, const short* __restrict__ u1t,
    const float* __restrict__ ub1, const short* __restrict__ u2t,
    const float* __restrict__ ub2, float* __restrict__ vb,
    const short* __restrict__ lwt_next, unsigned short* __restrict__ vproj, int N_) {
    __shared__ __align__(16) short t1_s[32 * 136];
    __shared__ __align__(16) short t2_s[32 * 136];
    const int tid = threadIdx.x;
    const int lane = tid & 63, wave = tid >> 6;
    const int l15 = lane & 15, l4 = lane >> 4;
    const int n0 = wave * 32;
    const int nb0 = blockIdx.x * 32;

    // GEMM1: t1 = ssp(agg @ u1 + ub1)
    {
        bf16x8 bw[2][4];
        float bias[2];
#pragma unroll
        for (int n = 0; n < 2; n++) {
            bias[n] = ub1[n0 + n * 16 + l15];
#pragma unroll
            for (int ks = 0; ks < 4; ks++)
                bw[n][ks] = *(const bf16x8*)&u1t[(n0 + n * 16 + l15) * 128 + ks * 32 + l4 * 8];
        }
#pragma unroll
        for (int m = 0; m < 2; m++) {
            int arow = nb0 + m * 16 + l15;
            const float* ap = &agg[(size_t)(arow < N_ ? arow : 0) * FF];
            f32x4 acc0 = {bias[0], bias[0], bias[0], bias[0]};
            f32x4 acc1 = {bias[1], bias[1], bias[1], bias[1]};
#pragma unroll
            for (int ks = 0; ks < 4; ks++) {
                float4 x0 = *(const float4*)&ap[ks * 32 + l4 * 8];
                float4 x1 = *(const float4*)&ap[ks * 32 + l4 * 8 + 4];
                bf16x8 a = {f2bf(x0.x), f2bf(x0.y), f2bf(x0.z), f2bf(x0.w),
                            f2bf(x1.x), f2bf(x1.y), f2bf(x1.z), f2bf(x1.w)};
                acc0 = __builtin_amdgcn_mfma_f32_16x16x32_bf16(a, bw[0][ks], acc0, 0, 0, 0);
                acc1 = __builtin_amdgcn_mfma_f32_16x16x32_bf16(a, bw[1][ks], acc1, 0, 0, 0);
            }
#pragma unroll
            for (int r = 0; r < 4; r++) {
                int er = m * 16 + l4 * 4 + r;
                t1_s[er * 136 + n0 + l15] = f2bf(ssp(acc0[r]));
                t1_s[er * 136 + n0 + 16 + l15] = f2bf(ssp(acc1[r]));
            }
        }
    }
    __syncthreads();

    // GEMM2: v_new = v + (t1 @ u2 + ub2)
    {
        bf16x8 bw[2][4];
        float bias[2];
#pragma unroll
        for (int n = 0; n < 2; n++) {
            bias[n] = ub2[n0 + n * 16 + l15];
#pragma unroll
            for (int ks = 0; ks < 4; ks++)
                bw[n][ks] = *(const bf16x8*)&u2t[(n0 + n * 16 + l15) * 128 + ks * 32 + l4 * 8];
        }
#pragma unroll
        for (int m = 0; m < 2; m++) {
            f32x4 acc0 = {bias[0], bias[0], bias[0], bias[0]};
            f32x4 acc1 = {bias[1], bias[1], bias[1], bias[1]};
#pragma unroll
            for (int ks = 0; ks < 4; ks++) {
                bf16x8 a = *(const bf16x8*)&t1_s[(m * 16 + l15) * 136 + ks * 32 + l4 * 8];
                acc0 = __builtin_amdgcn_mfma_f32_16x16x32_bf16(a, bw[0][ks], acc0, 0, 0, 0);
                acc1 = __builtin_amdgcn_mfma_f32_16x16x32_bf16(a, bw[1][ks], acc1, 0, 0, 0);
            }
#pragma unroll
            for (int r = 0; r < 4; r++) {
                int er = m * 16 + l4 * 4 + r;
                int gn = nb0 + er;
                if (gn < N_) {
                    size_t i0 = (size_t)gn * HH + n0 + l15;
                    size_t i1 = (size_t)gn * HH + n0 + 16 + l15;
                    float v0 = vb[i0] + acc0[r];
                    float v1 = vb[i1] + acc1[r];
                    vb[i0] = v0;
                    vb[i1] = v1;
                    t2_s[er * 136 + n0 + l15] = f2bf(v0);
                    t2_s[er * 136 + n0 + 16 + l15] = f2bf(v1);
                } else {
                    t2_s[er * 136 + n0 + l15] = 0;
                    t2_s[er * 136 + n0 + 16 + l15] = 0;
                }
            }
        }
    }
    __syncthreads();

    // GEMM3: vproj_next = v_new @ lin_w[l+1] (bf16 out)
    if (lwt_next) {
        bf16x8 bw[2][4];
#pragma unroll
        for (int n = 0; n < 2; n++)
#pragma unroll
            for (int ks = 0; ks < 4; ks++)
                bw[n][ks] = *(const bf16x8*)&lwt_next[(n0 + n * 16 + l15) * 128 + ks * 32 + l4 * 8];
#pragma unroll
        for (int m = 0; m < 2; m++) {
            f32x4 acc0 = {0.f, 0.f, 0.f, 0.f}, acc1 = {0.f, 0.f, 0.f, 0.f};
#pragma unroll
            for (int ks = 0; ks < 4; ks++) {
                bf16x8 a = *(const bf16x8*)&t2_s[(m * 16 + l15) * 136 + ks * 32 + l4 * 8];
                acc0 = __builtin_amdgcn_mfma_f32_16x16x32_bf16(a, bw[0][ks], acc0, 0, 0, 0);
                acc1 = __builtin_amdgcn_mfma_f32_16x16x32_bf16(a, bw[1][ks], acc1, 0, 0, 0);
            }
#pragma unroll
            for (int r = 0; r < 4; r++) {
                int gn = nb0 + m * 16 + l4 * 4 + r;
                if (gn < N_) {
                    vproj[(size_t)gn * FF + n0 + l15] = (unsigned short)f2bf(acc0[r]);
                    vproj[(size_t)gn * FF + n0 + 16 + l15] = (unsigned short)f2bf(acc1[r]);
                }
            }
        }
    }
}

extern "C" void kernel_launch(void* const* d_in, const int* in_sizes, int n_in,
                              void* d_out, int out_size, void* d_ws, size_t ws_size,
                              hipStream_t stream) {
    const float* v = (const float*)d_in[0];
    const float* pos = (const float*)d_in[1];
    const float* offs = (const float*)d_in[2];
    const int* edges = (const int*)d_in[3];
    const float* lin_w = (const float*)d_in[4];
    const float* w1 = (const float*)d_in[5];
    const float* b1 = (const float*)d_in[6];
    const float* w2 = (const float*)d_in[7];
    const float* b2 = (const float*)d_in[8];
    const float* u1 = (const float*)d_in[9];
    const float* ub1 = (const float*)d_in[10];
    const float* u2 = (const float*)d_in[11];
    const float* ub2 = (const float*)d_in[12];

    const int N = in_sizes[0] / HH;
    const int E = in_sizes[3] / 2;
    const int* row = edges;
    const int* col = edges + E;

    char* base = (char*)d_ws;
    int* counts = (int*)base;   base += (size_t)N * 4;
    int* woff = (int*)base;     base += (size_t)N * 4;
    int* srow = (int*)base;     base += (size_t)E * 4;
    int* scol = (int*)base;     base += (size_t)E * 4;
    float* sdist = (float*)base; base += (size_t)E * 4;
    float* sCb = (float*)base;  base += (size_t)E * 4;
    float* agg = (float*)base;  base += (size_t)N * FF * 4;
    float* vbuf = (float*)base; base += (size_t)N * HH * 4;
    unsigned short* vproj = (unsigned short*)base; base += (size_t)N * FF * 2;
    short* w1t = (short*)base;  base += (size_t)NLAYERS * FF * 64 * 2;
    short* w2t = (short*)base;  base += (size_t)NLAYERS * FF * FF * 2;
    short* u1t = (short*)base;  base += (size_t)NLAYERS * FF * FF * 2;
    short* u2t = (short*)base;  base += (size_t)NLAYERS * FF * FF * 2;
    short* lin_wt = (short*)base;

    const int EB = (E + 255) / 256;
    const int NB64 = (N + 63) / 64;
    const int NB32 = (N + 31) / 32;

    hipMemsetAsync(counts, 0, (size_t)N * 4, stream);
    hist_kernel<<<EB, 256, 0, stream>>>(col, counts, E);
    scan_kernel<<<1, 1024, 0, stream>>>(counts, woff, N);
    scatter_kernel<<<EB, 256, 0, stream>>>(pos, offs, row, col, woff, srow, scol,
                                           sdist, sCb, E);
    prep_kernel<<<(NLAYERS * FF * FF + 255) / 256, 256, 0, stream>>>(
        w1, w2, u1, u2, lin_w, w1t, w2t, u1t, u2t, lin_wt);
    hipMemcpyAsync(vbuf, v, (size_t)N * HH * sizeof(float),
                   hipMemcpyDeviceToDevice, stream);
    vproj0_kernel<<<NB64, 256, 0, stream>>>(v, lin_wt, vproj, N);

    for (int l = 0; l < NLAYERS; l++) {
        hipMemsetAsync(agg, 0, (size_t)N * FF * sizeof(float), stream);
        edge_mfma_kernel<<<(E + 63) / 64, 256, 0, stream>>>(
            sdist, sCb, vproj, srow, scol, w1t + (size_t)l * FF * 64,
            b1 + (size_t)l * FF, w2t + (size_t)l * FF * FF, b2 + (size_t)l * FF,
            agg, E);
        node_mfma_kernel<<<NB32, 256, 0, stream>>>(
            agg, u1t + (size_t)l * FF * FF, ub1 + (size_t)l * HH,
            u2t + (size_t)l * FF * FF, ub2 + (size_t)l * HH, vbuf,
            (l + 1 < NLAYERS) ? (lin_wt + (size_t)(l + 1) * FF * FF) : nullptr,
            vproj, N);
    }
    hipMemcpyAsync(d_out, vbuf, (size_t)N * HH * sizeof(float),
                   hipMemcpyDeviceToDevice, stream);
}